// Round 1
// baseline (4237.316 us; speedup 1.0000x reference)
//
#include <hip/hip_runtime.h>
#include <math.h>

constexpr int NN = 100000;   // nodes
constexpr int NE = 1600000;  // edges
constexpr int DI = 128;      // input dim
constexpr int DH = 128;      // hidden dim
constexpr int NC = 64;       // classes

// ---------------------------------------------------------------------------
// Kernel 1: z1 = l2normalize(x) @ W1 + b1
// One wave per row. W1 (64KB) staged in LDS per block, amortized via
// grid-stride. Lane computes outputs t=lane and t=lane+64 (stride-1 LDS
// reads across lanes -> free 2-way bank aliasing).
// ---------------------------------------------------------------------------
__global__ __launch_bounds__(256) void k_norm_gemm1(
    const float* __restrict__ x, const float* __restrict__ W1,
    const float* __restrict__ b1, float* __restrict__ z1)
{
    __shared__ float sW[DI * DH];    // 64 KB
    __shared__ float sx[4][DI];      // per-wave normalized row

    const int tid = threadIdx.x;
    // cooperative W1 load, float4-vectorized
    const float4* W4 = (const float4*)W1;
    float4* sW4 = (float4*)sW;
    for (int i = tid; i < DI * DH / 4; i += 256) sW4[i] = W4[i];
    __syncthreads();

    const int wave = tid >> 6, lane = tid & 63;
    const float bias0 = b1[lane];
    const float bias1 = b1[64 + lane];

    for (int row = blockIdx.x * 4 + wave; row < NN; row += gridDim.x * 4) {
        float a0 = x[(size_t)row * DI + lane];
        float a1 = x[(size_t)row * DI + 64 + lane];
        float ss = a0 * a0 + a1 * a1;
        #pragma unroll
        for (int off = 32; off; off >>= 1) ss += __shfl_xor(ss, off);
        const float rinv = 1.0f / fmaxf(sqrtf(ss), 1e-12f);
        // per-wave LDS region; intra-wave ds_write->ds_read ordered by lgkmcnt
        sx[wave][lane]      = a0 * rinv;
        sx[wave][64 + lane] = a1 * rinv;

        float acc0 = bias0, acc1 = bias1;
        const float* xr = sx[wave];
        #pragma unroll
        for (int k = 0; k < DI; k += 4) {
            const float4 xk = *(const float4*)(xr + k);
            acc0 += xk.x * sW[(k + 0) * DH + lane];
            acc1 += xk.x * sW[(k + 0) * DH + 64 + lane];
            acc0 += xk.y * sW[(k + 1) * DH + lane];
            acc1 += xk.y * sW[(k + 1) * DH + 64 + lane];
            acc0 += xk.z * sW[(k + 2) * DH + lane];
            acc1 += xk.z * sW[(k + 2) * DH + 64 + lane];
            acc0 += xk.w * sW[(k + 3) * DH + lane];
            acc1 += xk.w * sW[(k + 3) * DH + 64 + lane];
        }
        z1[(size_t)row * DH + lane]      = acc0;
        z1[(size_t)row * DH + 64 + lane] = acc1;
    }
}

// ---------------------------------------------------------------------------
// SPMM scatter: out[dst[e]] += w[e] * h[src[e]]   (D = 128 or 64)
// D/4 threads per edge, float4 gather, 4 HW fp32 atomics.
// ---------------------------------------------------------------------------
template <int D>
__global__ __launch_bounds__(256) void k_spmm(
    const float* __restrict__ h, const int* __restrict__ src,
    const int* __restrict__ dst, const float* __restrict__ ew,
    float* __restrict__ out)
{
    constexpr int CH = D / 4;
    const int total = NE * CH;  // <= 51.2M, fits int32
    for (int i = blockIdx.x * 256 + threadIdx.x; i < total;
         i += gridDim.x * 256) {
        const int e = i / CH;          // CH is pow2 -> shift
        const int c = i - e * CH;
        const int s = src[e];
        const int d = dst[e];
        const float wt = ew[e];
        const float4 v = *(const float4*)(h + (size_t)s * D + c * 4);
        float* o = out + (size_t)d * D + c * 4;
        unsafeAtomicAdd(o + 0, v.x * wt);
        unsafeAtomicAdd(o + 1, v.y * wt);
        unsafeAtomicAdd(o + 2, v.z * wt);
        unsafeAtomicAdd(o + 3, v.w * wt);
    }
}

// ---------------------------------------------------------------------------
// Kernel 3: z2 = relu(h) @ W2 + b2   (ReLU fused into row load)
// ---------------------------------------------------------------------------
__global__ __launch_bounds__(256) void k_gemm2(
    const float* __restrict__ h, const float* __restrict__ W2,
    const float* __restrict__ b2, float* __restrict__ z2)
{
    __shared__ float sW[DH * NC];   // 32 KB
    __shared__ float sh[4][DH];

    const int tid = threadIdx.x;
    const float4* W4 = (const float4*)W2;
    float4* sW4 = (float4*)sW;
    for (int i = tid; i < DH * NC / 4; i += 256) sW4[i] = W4[i];
    __syncthreads();

    const int wave = tid >> 6, lane = tid & 63;
    const float bias = b2[lane];

    for (int row = blockIdx.x * 4 + wave; row < NN; row += gridDim.x * 4) {
        const float h0 = fmaxf(h[(size_t)row * DH + lane], 0.0f);
        const float h1 = fmaxf(h[(size_t)row * DH + 64 + lane], 0.0f);
        sh[wave][lane]      = h0;
        sh[wave][64 + lane] = h1;

        float acc = bias;
        const float* hr = sh[wave];
        #pragma unroll
        for (int k = 0; k < DH; k += 4) {
            const float4 xk = *(const float4*)(hr + k);
            acc += xk.x * sW[(k + 0) * NC + lane];
            acc += xk.y * sW[(k + 1) * NC + lane];
            acc += xk.z * sW[(k + 2) * NC + lane];
            acc += xk.w * sW[(k + 3) * NC + lane];
        }
        z2[(size_t)row * NC + lane] = acc;
    }
}

// ---------------------------------------------------------------------------
// Kernel 5: in-place row softmax over 64 classes; wave per row
// ---------------------------------------------------------------------------
__global__ __launch_bounds__(256) void k_softmax(float* __restrict__ out)
{
    const int row = blockIdx.x * 4 + (threadIdx.x >> 6);
    if (row >= NN) return;
    const int lane = threadIdx.x & 63;
    const float v = out[(size_t)row * NC + lane];
    float m = v;
    #pragma unroll
    for (int off = 32; off; off >>= 1) m = fmaxf(m, __shfl_xor(m, off));
    const float e = __expf(v - m);
    float s = e;
    #pragma unroll
    for (int off = 32; off; off >>= 1) s += __shfl_xor(s, off);
    out[(size_t)row * NC + lane] = e / s;
}

// ---------------------------------------------------------------------------
extern "C" void kernel_launch(void* const* d_in, const int* in_sizes, int n_in,
                              void* d_out, int out_size, void* d_ws,
                              size_t ws_size, hipStream_t stream)
{
    const float* x  = (const float*)d_in[0];
    const int* src  = (const int*)d_in[1];
    const int* dst  = (const int*)d_in[2];
    const float* ew = (const float*)d_in[3];
    const float* W1 = (const float*)d_in[4];
    const float* b1 = (const float*)d_in[5];
    const float* W2 = (const float*)d_in[6];
    const float* b2 = (const float*)d_in[7];
    float* out = (float*)d_out;

    // workspace layout: z1[NN*DH] | agg1[NN*DH]; z2 reuses z1 (dead after spmm1)
    float* z1   = (float*)d_ws;
    float* agg1 = z1 + (size_t)NN * DH;
    float* z2   = z1;

    hipMemsetAsync(agg1, 0, (size_t)NN * DH * sizeof(float), stream);
    hipMemsetAsync(out, 0, (size_t)NN * NC * sizeof(float), stream);

    k_norm_gemm1<<<2048, 256, 0, stream>>>(x, W1, b1, z1);
    k_spmm<DH><<<8192, 256, 0, stream>>>(z1, src, dst, ew, agg1);
    k_gemm2<<<2048, 256, 0, stream>>>(agg1, W2, b2, z2);
    k_spmm<NC><<<8192, 256, 0, stream>>>(z2, src, dst, ew, out);
    k_softmax<<<(NN + 3) / 4, 256, 0, stream>>>(out);
}

// Round 2
// 674.638 us; speedup vs baseline: 6.2809x; 6.2809x over previous
//
#include <hip/hip_runtime.h>
#include <math.h>

constexpr int NN = 100000;   // nodes
constexpr int NE = 1600000;  // edges
constexpr int DI = 128;      // input dim
constexpr int DH = 128;      // hidden dim
constexpr int NC = 64;       // classes
constexpr int NB = (NN + 255) / 256;   // 391 scan blocks

// ---------------------------------------------------------------------------
// Kernel 1: z1 = l2normalize(x) @ W1 + b1  (unchanged from round 0)
// ---------------------------------------------------------------------------
__global__ __launch_bounds__(256) void k_norm_gemm1(
    const float* __restrict__ x, const float* __restrict__ W1,
    const float* __restrict__ b1, float* __restrict__ z1)
{
    __shared__ float sW[DI * DH];    // 64 KB
    __shared__ float sx[4][DI];

    const int tid = threadIdx.x;
    const float4* W4 = (const float4*)W1;
    float4* sW4 = (float4*)sW;
    for (int i = tid; i < DI * DH / 4; i += 256) sW4[i] = W4[i];
    __syncthreads();

    const int wave = tid >> 6, lane = tid & 63;
    const float bias0 = b1[lane];
    const float bias1 = b1[64 + lane];

    for (int row = blockIdx.x * 4 + wave; row < NN; row += gridDim.x * 4) {
        float a0 = x[(size_t)row * DI + lane];
        float a1 = x[(size_t)row * DI + 64 + lane];
        float ss = a0 * a0 + a1 * a1;
        #pragma unroll
        for (int off = 32; off; off >>= 1) ss += __shfl_xor(ss, off);
        const float rinv = 1.0f / fmaxf(sqrtf(ss), 1e-12f);
        sx[wave][lane]      = a0 * rinv;
        sx[wave][64 + lane] = a1 * rinv;

        float acc0 = bias0, acc1 = bias1;
        const float* xr = sx[wave];
        #pragma unroll
        for (int k = 0; k < DI; k += 4) {
            const float4 xk = *(const float4*)(xr + k);
            acc0 += xk.x * sW[(k + 0) * DH + lane];
            acc1 += xk.x * sW[(k + 0) * DH + 64 + lane];
            acc0 += xk.y * sW[(k + 1) * DH + lane];
            acc1 += xk.y * sW[(k + 1) * DH + 64 + lane];
            acc0 += xk.z * sW[(k + 2) * DH + lane];
            acc1 += xk.z * sW[(k + 2) * DH + 64 + lane];
            acc0 += xk.w * sW[(k + 3) * DH + lane];
            acc1 += xk.w * sW[(k + 3) * DH + 64 + lane];
        }
        z1[(size_t)row * DH + lane]      = acc0;
        z1[(size_t)row * DH + 64 + lane] = acc1;
    }
}

// ---------------------------------------------------------------------------
// CSR build: histogram -> 3-kernel exclusive scan -> (src,w) scatter
// ---------------------------------------------------------------------------
__global__ __launch_bounds__(256) void k_hist(
    const int* __restrict__ dst, int* __restrict__ cnt)
{
    for (int e = blockIdx.x * 256 + threadIdx.x; e < NE; e += gridDim.x * 256)
        atomicAdd(&cnt[dst[e]], 1);
}

__global__ __launch_bounds__(256) void k_scanA(
    const int* __restrict__ cnt, int* __restrict__ rowptr,
    int* __restrict__ bsum)
{
    __shared__ int tmp[256];
    const int t = threadIdx.x;
    const int gid = blockIdx.x * 256 + t;
    const int v = (gid < NN) ? cnt[gid] : 0;
    tmp[t] = v;
    __syncthreads();
    #pragma unroll
    for (int off = 1; off < 256; off <<= 1) {
        const int add = (t >= off) ? tmp[t - off] : 0;
        __syncthreads();
        tmp[t] += add;
        __syncthreads();
    }
    if (gid < NN) rowptr[gid] = tmp[t] - v;      // block-local exclusive
    if (t == 255) bsum[blockIdx.x] = tmp[255];   // block total
}

__global__ __launch_bounds__(512) void k_scanB(int* __restrict__ bsum)
{
    __shared__ int tmp[512];
    const int t = threadIdx.x;
    const int v = (t < NB) ? bsum[t] : 0;
    tmp[t] = v;
    __syncthreads();
    #pragma unroll
    for (int off = 1; off < 512; off <<= 1) {
        const int add = (t >= off) ? tmp[t - off] : 0;
        __syncthreads();
        tmp[t] += add;
        __syncthreads();
    }
    if (t < NB) bsum[t] = tmp[t] - v;            // exclusive block offsets
}

__global__ __launch_bounds__(256) void k_scanC(
    int* __restrict__ rowptr, const int* __restrict__ bsum,
    int* __restrict__ offs)
{
    const int gid = blockIdx.x * 256 + threadIdx.x;
    if (gid < NN) {
        const int r = rowptr[gid] + bsum[blockIdx.x];
        rowptr[gid] = r;
        offs[gid]   = r;      // running cursor for the scatter
    }
    if (gid == 0) rowptr[NN] = NE;
}

__global__ __launch_bounds__(256) void k_scatter(
    const int* __restrict__ src, const int* __restrict__ dst,
    const float* __restrict__ ew, int* __restrict__ offs,
    int2* __restrict__ srcw)
{
    for (int e = blockIdx.x * 256 + threadIdx.x; e < NE; e += gridDim.x * 256) {
        const int pos = atomicAdd(&offs[dst[e]], 1);
        srcw[pos] = make_int2(src[e], __float_as_int(ew[e]));
    }
}

// ---------------------------------------------------------------------------
// Gather-SPMM, D=128, ReLU fused: out[row] = relu(sum_e w_e * h[src_e])
// One wave per row; lane covers dims (lane, lane+64).
// ---------------------------------------------------------------------------
__global__ __launch_bounds__(256) void k_spmm1_csr(
    const float* __restrict__ h, const int* __restrict__ rowptr,
    const int2* __restrict__ srcw, float* __restrict__ out)
{
    const int row = blockIdx.x * 4 + (threadIdx.x >> 6);
    if (row >= NN) return;
    const int lane = threadIdx.x & 63;
    const int start = rowptr[row], end = rowptr[row + 1];
    float acc0 = 0.f, acc1 = 0.f;
    for (int e = start; e < end; ++e) {
        const int2 sw = srcw[e];                   // wave-uniform broadcast
        const float w = __int_as_float(sw.y);
        const float* hp = h + (size_t)sw.x * DH;
        acc0 = fmaf(w, hp[lane],      acc0);       // coalesced 256B
        acc1 = fmaf(w, hp[64 + lane], acc1);       // coalesced 256B
    }
    out[(size_t)row * DH + lane]      = fmaxf(acc0, 0.f);
    out[(size_t)row * DH + 64 + lane] = fmaxf(acc1, 0.f);
}

// ---------------------------------------------------------------------------
// z2 = h @ W2 + b2   (h already ReLU'd by spmm1)
// ---------------------------------------------------------------------------
__global__ __launch_bounds__(256) void k_gemm2(
    const float* __restrict__ h, const float* __restrict__ W2,
    const float* __restrict__ b2, float* __restrict__ z2)
{
    __shared__ float sW[DH * NC];   // 32 KB
    __shared__ float sh[4][DH];

    const int tid = threadIdx.x;
    const float4* W4 = (const float4*)W2;
    float4* sW4 = (float4*)sW;
    for (int i = tid; i < DH * NC / 4; i += 256) sW4[i] = W4[i];
    __syncthreads();

    const int wave = tid >> 6, lane = tid & 63;
    const float bias = b2[lane];

    for (int row = blockIdx.x * 4 + wave; row < NN; row += gridDim.x * 4) {
        sh[wave][lane]      = h[(size_t)row * DH + lane];
        sh[wave][64 + lane] = h[(size_t)row * DH + 64 + lane];

        float acc = bias;
        const float* hr = sh[wave];
        #pragma unroll
        for (int k = 0; k < DH; k += 4) {
            const float4 xk = *(const float4*)(hr + k);
            acc += xk.x * sW[(k + 0) * NC + lane];
            acc += xk.y * sW[(k + 1) * NC + lane];
            acc += xk.z * sW[(k + 2) * NC + lane];
            acc += xk.w * sW[(k + 3) * NC + lane];
        }
        z2[(size_t)row * NC + lane] = acc;
    }
}

// ---------------------------------------------------------------------------
// Gather-SPMM, D=64, softmax fused: out[row] = softmax(sum_e w_e * z2[src_e])
// ---------------------------------------------------------------------------
__global__ __launch_bounds__(256) void k_spmm2_softmax(
    const float* __restrict__ z2, const int* __restrict__ rowptr,
    const int2* __restrict__ srcw, float* __restrict__ out)
{
    const int row = blockIdx.x * 4 + (threadIdx.x >> 6);
    if (row >= NN) return;
    const int lane = threadIdx.x & 63;
    const int start = rowptr[row], end = rowptr[row + 1];
    float acc = 0.f;
    for (int e = start; e < end; ++e) {
        const int2 sw = srcw[e];
        acc = fmaf(__int_as_float(sw.y), z2[(size_t)sw.x * NC + lane], acc);
    }
    float m = acc;
    #pragma unroll
    for (int off = 32; off; off >>= 1) m = fmaxf(m, __shfl_xor(m, off));
    const float ex = __expf(acc - m);
    float s = ex;
    #pragma unroll
    for (int off = 32; off; off >>= 1) s += __shfl_xor(s, off);
    out[(size_t)row * NC + lane] = ex / s;
}

// ---------------------------------------------------------------------------
extern "C" void kernel_launch(void* const* d_in, const int* in_sizes, int n_in,
                              void* d_out, int out_size, void* d_ws,
                              size_t ws_size, hipStream_t stream)
{
    const float* x  = (const float*)d_in[0];
    const int* src  = (const int*)d_in[1];
    const int* dst  = (const int*)d_in[2];
    const float* ew = (const float*)d_in[3];
    const float* W1 = (const float*)d_in[4];
    const float* b1 = (const float*)d_in[5];
    const float* W2 = (const float*)d_in[6];
    const float* b2 = (const float*)d_in[7];
    float* out = (float*)d_out;

    // workspace layout (bytes):
    //   z1   [NN*DH*4]  = 51.2 MB   (z2 reuses this after spmm1)
    //   agg1 [NN*DH*4]  = 51.2 MB
    //   srcw [NE*8]     = 12.8 MB
    //   rowptr [(NN+1)*4], pad, offs/cnt [NN*4], bsum [512*4]
    char* base = (char*)d_ws;
    float* z1   = (float*)base;                       base += (size_t)NN * DH * 4;
    float* agg1 = (float*)base;                       base += (size_t)NN * DH * 4;
    int2*  srcw = (int2*)base;                        base += (size_t)NE * 8;
    int* rowptr = (int*)base;                         base += ((size_t)NN + 2) * 4;
    int* offs   = (int*)base;                         base += (size_t)NN * 4;   // aliases cnt
    int* bsum   = (int*)base;                         base += 512 * 4;
    int* cnt    = offs;                               // cnt dead after scanA
    float* z2   = z1;                                 // z1 dead after spmm1

    hipMemsetAsync(cnt, 0, (size_t)NN * 4, stream);

    k_norm_gemm1<<<2048, 256, 0, stream>>>(x, W1, b1, z1);

    k_hist   <<<2048, 256, 0, stream>>>(dst, cnt);
    k_scanA  <<<NB, 256, 0, stream>>>(cnt, rowptr, bsum);
    k_scanB  <<<1, 512, 0, stream>>>(bsum);
    k_scanC  <<<NB, 256, 0, stream>>>(rowptr, bsum, offs);
    k_scatter<<<2048, 256, 0, stream>>>(src, dst, ew, offs, srcw);

    k_spmm1_csr     <<<(NN + 3) / 4, 256, 0, stream>>>(z1, rowptr, srcw, agg1);
    k_gemm2         <<<2048, 256, 0, stream>>>(agg1, W2, b2, z2);
    k_spmm2_softmax <<<(NN + 3) / 4, 256, 0, stream>>>(z2, rowptr, srcw, out);
}